// Round 1
// 1178.898 us; speedup vs baseline: 1.0136x; 1.0136x over previous
//
#include <hip/hip_runtime.h>
#include <hip/hip_bf16.h>
#include <cstdint>
#include <cstddef>

typedef __attribute__((ext_vector_type(4))) float floatx4;
typedef __attribute__((ext_vector_type(8))) __bf16 bf16x8;

#define BS 8
#define SEQ 2048
#define M_TOT 16384
#define DK 4096
#define DN 4096
#define NSK 8
#define RANK 16

__device__ __forceinline__ unsigned short f2bf(float f) {
  union { __hip_bfloat16 h; unsigned short u; } v;
  v.h = __float2bfloat16(f);
  return v.u;
}

// async 16B global->LDS (wave-uniform LDS base + lane*16)
__device__ __forceinline__ void async16(const void* g, void* l) {
  __builtin_amdgcn_global_load_lds(
      (const __attribute__((address_space(1))) unsigned int*)g,
      (__attribute__((address_space(3))) unsigned int*)l, 16, 0, 0);
}

// ---------------------------------------------------------------------------
// 1. Mixing weights: mw[b][s] = sigmoid(logits[task[b]][s]) normalized per b.
__global__ void prep_mw_kernel(const float* __restrict__ logits,
                               const void* __restrict__ task_raw,
                               float* __restrict__ mw) {
  const int* t32 = (const int*)task_raw;
  bool is64 = true;
#pragma unroll
  for (int b = 0; b < BS; ++b)
    if (t32[2 * b + 1] != 0) is64 = false;  // high words nonzero => int32 data
  int tid = threadIdx.x;        // 64 threads: 8 batches x 8 skills
  int b = tid >> 3, s = tid & 7;
  int task = is64 ? t32[2 * b] : t32[b];
  float lg = logits[task * NSK + s];
  float sg = 1.0f / (1.0f + expf(-lg));
  float sum = sg;
  sum += __shfl_xor(sum, 1);
  sum += __shfl_xor(sum, 2);
  sum += __shfl_xor(sum, 4);
  mw[tid] = sg / (sum + 1e-12f);
}

// ---------------------------------------------------------------------------
// 2a. A_bfT[b][r][d] = bf16( sum_s mw[b][s] * lora_a[s][d][r] )   (16 x 4096)
__global__ __launch_bounds__(256) void prep_a_kernel(
    const float* __restrict__ lora_a, const float* __restrict__ mw,
    unsigned short* __restrict__ a_bft) {
  int b = blockIdx.y;
  int d = blockIdx.x * 256 + threadIdx.x;
  float w[NSK];
#pragma unroll
  for (int s = 0; s < NSK; ++s) w[s] = mw[b * NSK + s];
  float acc[RANK];
#pragma unroll
  for (int r = 0; r < RANK; ++r) acc[r] = 0.f;
  for (int s = 0; s < NSK; ++s) {
    const float4* p = (const float4*)&lora_a[((size_t)s * DK + d) * RANK];
#pragma unroll
    for (int q = 0; q < 4; ++q) {
      float4 v = p[q];
      acc[q * 4 + 0] += w[s] * v.x;
      acc[q * 4 + 1] += w[s] * v.y;
      acc[q * 4 + 2] += w[s] * v.z;
      acc[q * 4 + 3] += w[s] * v.w;
    }
  }
#pragma unroll
  for (int r = 0; r < RANK; ++r)
    a_bft[((size_t)b * RANK + r) * DK + d] = f2bf(acc[r]);
}

// 2b. baug[b][n][0..31]: r<16 -> bf16( (sum_s mw*lora_b[s][r][n]) / 16 ), else 0
__global__ __launch_bounds__(256) void prep_b_kernel(
    const float* __restrict__ lora_b, const float* __restrict__ mw,
    unsigned short* __restrict__ baug) {
  int b = blockIdx.y;
  int n = blockIdx.x * 256 + threadIdx.x;
  float w[NSK];
#pragma unroll
  for (int s = 0; s < NSK; ++s) w[s] = mw[b * NSK + s];
  unsigned short ov[32];
#pragma unroll
  for (int r = 0; r < RANK; ++r) {
    float acc = 0.f;
#pragma unroll
    for (int s = 0; s < NSK; ++s)
      acc += w[s] * lora_b[((size_t)s * RANK + r) * DN + n];
    ov[r] = f2bf(acc * 0.0625f);  // fold the /rank here
  }
#pragma unroll
  for (int r = RANK; r < 32; ++r) ov[r] = 0;
  uint4* dst = (uint4*)&baug[((size_t)b * DN + n) * 32];
  const uint4* sv = (const uint4*)ov;
  dst[0] = sv[0]; dst[1] = sv[1]; dst[2] = sv[2]; dst[3] = sv[3];
}

// ---------------------------------------------------------------------------
// 3. fp32 -> bf16 bulk conversion (float4 in, ushort4 out), grid-stride
__global__ __launch_bounds__(256) void conv_f32_to_bf16(
    const float* __restrict__ src, unsigned short* __restrict__ dst,
    long long n4) {
  long long stride = (long long)gridDim.x * 256;
  for (long long i = (long long)blockIdx.x * 256 + threadIdx.x; i < n4; i += stride) {
    float4 v = ((const float4*)src)[i];
    ushort4 o;
    o.x = f2bf(v.x); o.y = f2bf(v.y); o.z = f2bf(v.z); o.w = f2bf(v.w);
    ((ushort4*)dst)[i] = o;
  }
}

// ---------------------------------------------------------------------------
// 4. t[16384][16] = xb @ A_bfT^T via MFMA, K split 4 ways, fp32 atomics.
__global__ __launch_bounds__(256) void t_gemm_kernel(
    const unsigned short* __restrict__ xb, const unsigned short* __restrict__ abft,
    float* __restrict__ t_f32) {
  const int wave = threadIdx.x >> 6;
  const int lane = threadIdx.x & 63;
  const int mtile = blockIdx.x * 4 + wave;  // 0..1023
  const int row0 = mtile * 16;
  const int b = row0 >> 11;                 // /2048
  const int k0 = blockIdx.y * 1024;
  const int fr = lane & 15;
  const int fq = (lane >> 4) * 8;
  const unsigned short* pa = xb + (size_t)(row0 + fr) * DK + fq + k0;
  const unsigned short* pb = abft + ((size_t)b * RANK + fr) * DK + fq + k0;
  floatx4 acc = {0.f, 0.f, 0.f, 0.f};
  for (int k = 0; k < 1024; k += 32) {
    bf16x8 av = *(const bf16x8*)(pa + k);
    bf16x8 bv = *(const bf16x8*)(pb + k);
    acc = __builtin_amdgcn_mfma_f32_16x16x32_bf16(av, bv, acc, 0, 0, 0);
  }
  const int col = lane & 15;
  const int rowq = (lane >> 4) * 4;
#pragma unroll
  for (int j = 0; j < 4; ++j)
    atomicAdd(&t_f32[(size_t)(row0 + rowq + j) * RANK + col], acc[j]);
}

// 5. taug[row][0..31]: r<16 -> bf16(t), else 0
__global__ __launch_bounds__(256) void t_final_kernel(
    const float* __restrict__ t_f32, unsigned short* __restrict__ taug) {
  int i = blockIdx.x * 256 + threadIdx.x;  // 262144 total
  int row = i >> 4, r = i & 15;
  taug[(size_t)row * 32 + r] = f2bf(t_f32[i]);
  taug[(size_t)row * 32 + 16 + r] = 0;
}

// ---------------------------------------------------------------------------
// 6. Main GEMM — 256x256 tile, BK=64, 8 waves (2Mx4N, 128x64 per wave),
//    8-phase schedule (T3) + counted vmcnt(6) (T4) + 2-bit XOR LDS swizzle
//    (T2: byte bits 9,8 -> bits 5,4; linear gload_lds dest + pre-swizzled
//    global source + swizzled ds_read, rule 21) + setprio around MFMA (T5)
//    + bijective XCD swizzle (T1). Adapter (x@A)@B/16 applied as a direct
//    register MFMA round from taug/baug in the epilogue (L2-resident, no
//    staging). LDS 128 KiB: [2 dbuf][A 32K | B 32K], each [h][kh][128][32].
//
//    Schedule invariants (per-wave load issue order, steady state, tile kt):
//      P4 of kt-1: (kt+1).H1-3 (6 loads) -> vmcnt(6)
//      P1 of kt  : (kt+1).H4   (2 loads)
//      P4 of kt  : (kt+2).H1-3 (6 loads) -> vmcnt(6) drains all of tile kt+1
//    Stages into the buffer under compute (P4) are issued after that
//    buffer's last ds_read phase (P3) end-barrier; P4's MFMA is reg-only.
__global__ __launch_bounds__(512, 2) void main_gemm(
    const unsigned short* __restrict__ xb, const unsigned short* __restrict__ wb,
    const unsigned short* __restrict__ taug, const unsigned short* __restrict__ baug,
    const float* __restrict__ bias, float* __restrict__ out) {
  __shared__ __align__(1024) unsigned short lds[65536];  // 128 KiB

  const int tid = threadIdx.x;
  const int wave = tid >> 6;
  const int lane = tid & 63;
  const int wm = wave >> 2;          // 0..1 -> rows wm*128..+128
  const int wn = wave & 3;           // 0..3 -> cols wn*64..+64
  const int fr = lane & 15;
  const int fq = (lane >> 4) << 3;   // 0,8,16,24 (bf16 k-offset)
  const int swz = (lane & 12) << 1;  // ushort-index XOR (row bits 3,2 -> 32B,16B)

  // XCD-aware bijective swizzle: nwg = 1024 = 8 * 128
  const int orig = blockIdx.x;
  const int swb = (orig & 7) * 128 + (orig >> 3);
  const int tile_m = swb >> 4;       // 0..63
  const int tile_n = swb & 15;       // 0..15
  const int m0 = tile_m * 256;
  const int n0 = tile_n * 256;
  const int batch = tile_m >> 3;     // 2048 rows per batch, 8 tiles per batch

  // --- staging source precompute (involution pre-swizzle of global source) ---
  // lane l writes LDS bytes [l*16, l*16+16) of its 1024B subtile (linear);
  // it must source the data whose LOGICAL subtile offset is l*16 ^ f(l*16).
  const int l16 = lane << 4;
  const int o = l16 ^ ((l16 & 512) >> 4) ^ ((l16 & 256) >> 4);
  const int rin = o >> 6;            // row within 16-row subtile
  const int k2 = (o & 63) >> 1;      // bf16 col within 32-col subtile
  const int s0 = wave * 2, s1 = s0 + 1;   // this wave's 2 subtiles (of 16)
  // subtile s: kh = s>>3 (k 0-31 / 32-63), rg = s&7 (16-row group)
  const unsigned short* aS0 = xb + (size_t)(m0 + (s0 & 7) * 16 + rin) * DK + (s0 >> 3) * 32 + k2;
  const unsigned short* aS1 = xb + (size_t)(m0 + (s1 & 7) * 16 + rin) * DK + (s1 >> 3) * 32 + k2;
  const unsigned short* bS0 = wb + (size_t)(n0 + (s0 & 7) * 16 + rin) * DK + (s0 >> 3) * 32 + k2;
  const unsigned short* bS1 = wb + (size_t)(n0 + (s1 & 7) * 16 + rin) * DK + (s1 >> 3) * 32 + k2;

// stage half-tile h (128 rows) of A or B for K-tile kt into dbuf d (2 loads)
#define STG_A(d, h, kt) do {                                                        \
    async16(aS0 + (((size_t)(h)) << 19) + ((size_t)(kt) << 6),                      \
            &lds[(d) * 32768 + (h) * 8192 + s0 * 512]);                             \
    async16(aS1 + (((size_t)(h)) << 19) + ((size_t)(kt) << 6),                      \
            &lds[(d) * 32768 + (h) * 8192 + s1 * 512]);                             \
  } while (0)
#define STG_B(d, h, kt) do {                                                        \
    async16(bS0 + (((size_t)(h)) << 19) + ((size_t)(kt) << 6),                      \
            &lds[(d) * 32768 + 16384 + (h) * 8192 + s0 * 512]);                     \
    async16(bS1 + (((size_t)(h)) << 19) + ((size_t)(kt) << 6),                      \
            &lds[(d) * 32768 + 16384 + (h) * 8192 + s1 * 512]);                     \
  } while (0)

// swizzled fragment reads (16B, ds_read_b128)
#define RD_A(d, t, ks)                                                              \
  (*(const bf16x8*)&lds[(((d) * 32768) + wm * 8192 + (ks) * 4096 +                  \
                         ((t) * 16 + fr) * 32 + fq) ^ swz])
#define RD_B(d, u, ks)                                                              \
  (*(const bf16x8*)&lds[(((d) * 32768) + 16384 + (wn >> 1) * 8192 + (ks) * 4096 +   \
                         ((wn & 1) * 64 + (u) * 16 + fr) * 32 + fq) ^ swz])

  floatx4 acc[8][4];
#pragma unroll
  for (int t = 0; t < 8; ++t)
#pragma unroll
    for (int u = 0; u < 4; ++u) acc[t][u] = (floatx4){0.f, 0.f, 0.f, 0.f};

  bf16x8 a[4][2];    // A frags of current rowhalf (t x ks)
  bf16x8 b0[2][2];   // B frags cols 0-31 of wave (u x ks)
  bf16x8 b1[2][2];   // B frags cols 32-63 of wave

  // --- prologue: tile0 H1-4, tile1 H1-3; drain tile0 (6 left in flight) ---
  STG_A(0, 0, 0); STG_A(0, 1, 0); STG_B(0, 0, 0); STG_B(0, 1, 0);
  STG_A(1, 0, 1); STG_A(1, 1, 1); STG_B(1, 0, 1);
  asm volatile("s_waitcnt vmcnt(6)" ::: "memory");
  __builtin_amdgcn_s_barrier();

#define TILE(d, kt) do {                                                            \
    /* ---- P1: quadrant (rh0, ch0); stage H4 of tile kt+1 ---- */                  \
    _Pragma("unroll")                                                               \
    for (int t = 0; t < 4; ++t) { a[t][0] = RD_A(d, t, 0); a[t][1] = RD_A(d, t, 1); } \
    _Pragma("unroll")                                                               \
    for (int u = 0; u < 2; ++u) { b0[u][0] = RD_B(d, u, 0); b0[u][1] = RD_B(d, u, 1); } \
    if ((kt) + 1 < 64) STG_B(1 - (d), 1, (kt) + 1);                                 \
    __builtin_amdgcn_s_barrier();                                                   \
    asm volatile("s_waitcnt lgkmcnt(0)" ::: "memory");                              \
    __builtin_amdgcn_s_setprio(1);                                                  \
    _Pragma("unroll")                                                               \
    for (int t = 0; t < 4; ++t)                                                     \
      _Pragma("unroll")                                                             \
      for (int u = 0; u < 2; ++u) {                                                 \
        acc[t][u] = __builtin_amdgcn_mfma_f32_16x16x32_bf16(a[t][0], b0[u][0], acc[t][u], 0, 0, 0); \
        acc[t][u] = __builtin_amdgcn_mfma_f32_16x16x32_bf16(a[t][1], b0[u][1], acc[t][u], 0, 0, 0); \
      }                                                                             \
    __builtin_amdgcn_s_setprio(0);                                                  \
    __builtin_amdgcn_s_barrier();                                                   \
    /* ---- P2: quadrant (rh0, ch1) ---- */                                         \
    _Pragma("unroll")                                                               \
    for (int u = 0; u < 2; ++u) { b1[u][0] = RD_B(d, u + 2, 0); b1[u][1] = RD_B(d, u + 2, 1); } \
    __builtin_amdgcn_s_barrier();                                                   \
    asm volatile("s_waitcnt lgkmcnt(0)" ::: "memory");                              \
    __builtin_amdgcn_s_setprio(1);                                                  \
    _Pragma("unroll")                                                               \
    for (int t = 0; t < 4; ++t)                                                     \
      _Pragma("unroll")                                                             \
      for (int u = 0; u < 2; ++u) {                                                 \
        acc[t][u + 2] = __builtin_amdgcn_mfma_f32_16x16x32_bf16(a[t][0], b1[u][0], acc[t][u + 2], 0, 0, 0); \
        acc[t][u + 2] = __builtin_amdgcn_mfma_f32_16x16x32_bf16(a[t][1], b1[u][1], acc[t][u + 2], 0, 0, 0); \
      }                                                                             \
    __builtin_amdgcn_s_setprio(0);                                                  \
    __builtin_amdgcn_s_barrier();                                                   \
    /* ---- P3: quadrant (rh1, ch0) ---- */                                         \
    _Pragma("unroll")                                                               \
    for (int t = 0; t < 4; ++t) { a[t][0] = RD_A(d, t + 4, 0); a[t][1] = RD_A(d, t + 4, 1); } \
    __builtin_amdgcn_s_barrier();                                                   \
    asm volatile("s_waitcnt lgkmcnt(0)" ::: "memory");                              \
    __builtin_amdgcn_s_setprio(1);                                                  \
    _Pragma("unroll")                                                               \
    for (int t = 0; t < 4; ++t)                                                     \
      _Pragma("unroll")                                                             \
      for (int u = 0; u < 2; ++u) {                                                 \
        acc[t + 4][u] = __builtin_amdgcn_mfma_f32_16x16x32_bf16(a[t][0], b0[u][0], acc[t + 4][u], 0, 0, 0); \
        acc[t + 4][u] = __builtin_amdgcn_mfma_f32_16x16x32_bf16(a[t][1], b0[u][1], acc[t + 4][u], 0, 0, 0); \
      }                                                                             \
    __builtin_amdgcn_s_setprio(0);                                                  \
    __builtin_amdgcn_s_barrier();                                                   \
    /* ---- P4: stage H1-3 of tile kt+2 (safe: buf reads ended at P3);       */     \
    /*      counted vmcnt(6) covers everything tile kt+1 needs; reg-only MFMA */    \
    if ((kt) + 2 < 64) {                                                            \
      STG_A(d, 0, (kt) + 2); STG_A(d, 1, (kt) + 2); STG_B(d, 0, (kt) + 2);          \
      asm volatile("s_waitcnt vmcnt(6)" ::: "memory");                              \
    } else {                                                                        \
      asm volatile("s_waitcnt vmcnt(0)" ::: "memory");                              \
    }                                                                               \
    __builtin_amdgcn_s_barrier();                                                   \
    __builtin_amdgcn_s_setprio(1);                                                  \
    _Pragma("unroll")                                                               \
    for (int t = 0; t < 4; ++t)                                                     \
      _Pragma("unroll")                                                             \
      for (int u = 0; u < 2; ++u) {                                                 \
        acc[t + 4][u + 2] = __builtin_amdgcn_mfma_f32_16x16x32_bf16(a[t][0], b1[u][0], acc[t + 4][u + 2], 0, 0, 0); \
        acc[t + 4][u + 2] = __builtin_amdgcn_mfma_f32_16x16x32_bf16(a[t][1], b1[u][1], acc[t + 4][u + 2], 0, 0, 0); \
      }                                                                             \
    __builtin_amdgcn_s_setprio(0);                                                  \
    __builtin_amdgcn_s_barrier();                                                   \
  } while (0)

  for (int it = 0; it < 32; ++it) {
    const int kt0 = it * 2;
    TILE(0, kt0);
    TILE(1, kt0 + 1);
  }

  // --- adapter step: one K=32 MFMA round from taug/baug (cols 16-31 zero) ---
  {
    const unsigned short* tA = taug + (size_t)(m0 + wm * 128 + fr) * 32 + fq;
    const unsigned short* tB = baug + ((size_t)batch * DN + n0 + wn * 64 + fr) * 32 + fq;
    bf16x8 av[8], bv[4];
#pragma unroll
    for (int t = 0; t < 8; ++t) av[t] = *(const bf16x8*)(tA + (size_t)t * 512);
#pragma unroll
    for (int u = 0; u < 4; ++u) bv[u] = *(const bf16x8*)(tB + (size_t)u * 512);
#pragma unroll
    for (int t = 0; t < 8; ++t)
#pragma unroll
      for (int u = 0; u < 4; ++u)
        acc[t][u] = __builtin_amdgcn_mfma_f32_16x16x32_bf16(av[t], bv[u], acc[t][u], 0, 0, 0);
  }

  // --- epilogue: C/D layout col=lane&15, row=(lane>>4)*4+j; add bias ---
  const int rowq = (lane >> 4) * 4;
#pragma unroll
  for (int u = 0; u < 4; ++u) {
    const int col = n0 + wn * 64 + u * 16 + fr;
    const float bvv = bias[col];
#pragma unroll
    for (int t = 0; t < 8; ++t) {
      float* po = out + (size_t)(m0 + wm * 128 + t * 16 + rowq) * DN + col;
#pragma unroll
      for (int j = 0; j < 4; ++j) po[(size_t)j * DN] = acc[t][u][j] + bvv;
    }
  }
#undef TILE
#undef RD_A
#undef RD_B
#undef STG_A
#undef STG_B
}

// ---------------------------------------------------------------------------
extern "C" void kernel_launch(void* const* d_in, const int* in_sizes, int n_in,
                              void* d_out, int out_size, void* d_ws, size_t ws_size,
                              hipStream_t stream) {
  (void)in_sizes; (void)n_in; (void)out_size; (void)ws_size;
  const float* x             = (const float*)d_in[0];
  const float* weight        = (const float*)d_in[1];
  const float* bias          = (const float*)d_in[2];
  const float* module_logits = (const float*)d_in[3];
  const float* lora_a        = (const float*)d_in[4];
  const float* lora_b        = (const float*)d_in[5];
  const void*  task_ids      = d_in[6];
  float* out = (float*)d_out;

  // workspace layout (all 16B-aligned); total ~165 MB
  char* ws = (char*)d_ws;
  unsigned short* xb   = (unsigned short*)(ws);                  // 16384*4096*2 = 134217728
  unsigned short* wb   = (unsigned short*)(ws + 134217728);      // 4096*4096*2  = 33554432
  unsigned short* taug = (unsigned short*)(ws + 167772160);      // 16384*32*2   = 1048576
  unsigned short* baug = (unsigned short*)(ws + 168820736);      // 8*4096*32*2  = 2097152
  unsigned short* abft = (unsigned short*)(ws + 170917888);      // 8*16*4096*2  = 1048576
  float*          tf32 = (float*)(ws + 171966464);               // 16384*16*4   = 1048576
  float*          mw   = (float*)(ws + 173015040);               // 256

  hipLaunchKernelGGL(prep_mw_kernel, dim3(1), dim3(64), 0, stream,
                     module_logits, task_ids, mw);
  hipLaunchKernelGGL(prep_a_kernel, dim3(16, 8), dim3(256), 0, stream,
                     lora_a, mw, abft);
  hipLaunchKernelGGL(prep_b_kernel, dim3(16, 8), dim3(256), 0, stream,
                     lora_b, mw, baug);
  hipLaunchKernelGGL(conv_f32_to_bf16, dim3(2048), dim3(256), 0, stream,
                     weight, wb, (long long)(4096LL * 4096 / 4));
  hipLaunchKernelGGL(conv_f32_to_bf16, dim3(8192), dim3(256), 0, stream,
                     x, xb, (long long)(16384LL * 4096 / 4));
  hipMemsetAsync(tf32, 0, (size_t)M_TOT * RANK * sizeof(float), stream);
  hipLaunchKernelGGL(t_gemm_kernel, dim3(256, 4), dim3(256), 0, stream,
                     xb, abft, tf32);
  hipLaunchKernelGGL(t_final_kernel, dim3(1024), dim3(256), 0, stream,
                     tf32, taug);
  hipLaunchKernelGGL(main_gemm, dim3(1024), dim3(512), 0, stream,
                     xb, wb, taug, baug, bias, out);
}

// Round 2
// 1001.298 us; speedup vs baseline: 1.1933x; 1.1774x over previous
//
#include <hip/hip_runtime.h>
#include <hip/hip_bf16.h>
#include <cstdint>
#include <cstddef>

typedef __attribute__((ext_vector_type(4))) float floatx4;
typedef __attribute__((ext_vector_type(8))) __bf16 bf16x8;

#define BS 8
#define SEQ 2048
#define M_TOT 16384
#define DK 4096
#define DN 4096
#define NSK 8
#define RANK 16

__device__ __forceinline__ unsigned short f2bf(float f) {
  union { __hip_bfloat16 h; unsigned short u; } v;
  v.h = __float2bfloat16(f);
  return v.u;
}

// async 16B global->LDS (wave-uniform LDS base + lane*16)
__device__ __forceinline__ void async16(const void* g, void* l) {
  __builtin_amdgcn_global_load_lds(
      (const __attribute__((address_space(1))) unsigned int*)g,
      (__attribute__((address_space(3))) unsigned int*)l, 16, 0, 0);
}

// ---------------------------------------------------------------------------
// 1. Mixing weights: mw[b][s] = sigmoid(logits[task[b]][s]) normalized per b.
__global__ void prep_mw_kernel(const float* __restrict__ logits,
                               const void* __restrict__ task_raw,
                               float* __restrict__ mw) {
  const int* t32 = (const int*)task_raw;
  bool is64 = true;
#pragma unroll
  for (int b = 0; b < BS; ++b)
    if (t32[2 * b + 1] != 0) is64 = false;  // high words nonzero => int32 data
  int tid = threadIdx.x;        // 64 threads: 8 batches x 8 skills
  int b = tid >> 3, s = tid & 7;
  int task = is64 ? t32[2 * b] : t32[b];
  float lg = logits[task * NSK + s];
  float sg = 1.0f / (1.0f + expf(-lg));
  float sum = sg;
  sum += __shfl_xor(sum, 1);
  sum += __shfl_xor(sum, 2);
  sum += __shfl_xor(sum, 4);
  mw[tid] = sg / (sum + 1e-12f);
}

// ---------------------------------------------------------------------------
// 2a. A_bfT[b][r][d] = bf16( sum_s mw[b][s] * lora_a[s][d][r] )   (16 x 4096)
__global__ __launch_bounds__(256) void prep_a_kernel(
    const float* __restrict__ lora_a, const float* __restrict__ mw,
    unsigned short* __restrict__ a_bft) {
  int b = blockIdx.y;
  int d = blockIdx.x * 256 + threadIdx.x;
  float w[NSK];
#pragma unroll
  for (int s = 0; s < NSK; ++s) w[s] = mw[b * NSK + s];
  float acc[RANK];
#pragma unroll
  for (int r = 0; r < RANK; ++r) acc[r] = 0.f;
  for (int s = 0; s < NSK; ++s) {
    const float4* p = (const float4*)&lora_a[((size_t)s * DK + d) * RANK];
#pragma unroll
    for (int q = 0; q < 4; ++q) {
      float4 v = p[q];
      acc[q * 4 + 0] += w[s] * v.x;
      acc[q * 4 + 1] += w[s] * v.y;
      acc[q * 4 + 2] += w[s] * v.z;
      acc[q * 4 + 3] += w[s] * v.w;
    }
  }
#pragma unroll
  for (int r = 0; r < RANK; ++r)
    a_bft[((size_t)b * RANK + r) * DK + d] = f2bf(acc[r]);
}

// 2b. baug[b][n][0..31]: r<16 -> bf16( (sum_s mw*lora_b[s][r][n]) / 16 ), else 0
__global__ __launch_bounds__(256) void prep_b_kernel(
    const float* __restrict__ lora_b, const float* __restrict__ mw,
    unsigned short* __restrict__ baug) {
  int b = blockIdx.y;
  int n = blockIdx.x * 256 + threadIdx.x;
  float w[NSK];
#pragma unroll
  for (int s = 0; s < NSK; ++s) w[s] = mw[b * NSK + s];
  unsigned short ov[32];
#pragma unroll
  for (int r = 0; r < RANK; ++r) {
    float acc = 0.f;
#pragma unroll
    for (int s = 0; s < NSK; ++s)
      acc += w[s] * lora_b[((size_t)s * RANK + r) * DN + n];
    ov[r] = f2bf(acc * 0.0625f);  // fold the /rank here
  }
#pragma unroll
  for (int r = RANK; r < 32; ++r) ov[r] = 0;
  uint4* dst = (uint4*)&baug[((size_t)b * DN + n) * 32];
  const uint4* sv = (const uint4*)ov;
  dst[0] = sv[0]; dst[1] = sv[1]; dst[2] = sv[2]; dst[3] = sv[3];
}

// ---------------------------------------------------------------------------
// 3. fp32 -> bf16 bulk conversion (float4 in, ushort4 out), grid-stride
__global__ __launch_bounds__(256) void conv_f32_to_bf16(
    const float* __restrict__ src, unsigned short* __restrict__ dst,
    long long n4) {
  long long stride = (long long)gridDim.x * 256;
  for (long long i = (long long)blockIdx.x * 256 + threadIdx.x; i < n4; i += stride) {
    float4 v = ((const float4*)src)[i];
    ushort4 o;
    o.x = f2bf(v.x); o.y = f2bf(v.y); o.z = f2bf(v.z); o.w = f2bf(v.w);
    ((ushort4*)dst)[i] = o;
  }
}

// ---------------------------------------------------------------------------
// 4. t[16384][16] = xb @ A_bfT^T via MFMA, K split 4 ways, fp32 atomics.
__global__ __launch_bounds__(256) void t_gemm_kernel(
    const unsigned short* __restrict__ xb, const unsigned short* __restrict__ abft,
    float* __restrict__ t_f32) {
  const int wave = threadIdx.x >> 6;
  const int lane = threadIdx.x & 63;
  const int mtile = blockIdx.x * 4 + wave;  // 0..1023
  const int row0 = mtile * 16;
  const int b = row0 >> 11;                 // /2048
  const int k0 = blockIdx.y * 1024;
  const int fr = lane & 15;
  const int fq = (lane >> 4) * 8;
  const unsigned short* pa = xb + (size_t)(row0 + fr) * DK + fq + k0;
  const unsigned short* pb = abft + ((size_t)b * RANK + fr) * DK + fq + k0;
  floatx4 acc = {0.f, 0.f, 0.f, 0.f};
  for (int k = 0; k < 1024; k += 32) {
    bf16x8 av = *(const bf16x8*)(pa + k);
    bf16x8 bv = *(const bf16x8*)(pb + k);
    acc = __builtin_amdgcn_mfma_f32_16x16x32_bf16(av, bv, acc, 0, 0, 0);
  }
  const int col = lane & 15;
  const int rowq = (lane >> 4) * 4;
#pragma unroll
  for (int j = 0; j < 4; ++j)
    atomicAdd(&t_f32[(size_t)(row0 + rowq + j) * RANK + col], acc[j]);
}

// 5. taug[row][0..31]: r<16 -> bf16(t), else 0
__global__ __launch_bounds__(256) void t_final_kernel(
    const float* __restrict__ t_f32, unsigned short* __restrict__ taug) {
  int i = blockIdx.x * 256 + threadIdx.x;  // 262144 total
  int row = i >> 4, r = i & 15;
  taug[(size_t)row * 32 + r] = f2bf(t_f32[i]);
  taug[(size_t)row * 32 + 16 + r] = 0;
}

// ---------------------------------------------------------------------------
// 6. Main GEMM — 256x256 tile, BK=64, 8 waves (2Mx4N, 128x64 per wave),
//    8-phase schedule (T3) + counted vmcnt(6) (T4) + T2 st_16x32 swizzle
//    (ushort col ^= (row&7)<<3 — row bits 0,1,2 into byte bits 4,5,6, so
//    every consecutive 8-lane beat of a ds_read_b128 covers all 8 bank
//    groups) + setprio (T5) + bijective XCD swizzle (T1). Adapter applied
//    as a register MFMA round from taug/baug in the epilogue.
//
//    LDS per dbuf: A = [256 rows][64 ushort] (32KB), B same (32KB).
//    Physical ushort idx = row*64 + (col ^ ((row&7)<<3))  (involution/row).
//    Staging: 1024B chunk = 8 rows x 128B, linear gload_lds dest; lane l
//    sources global row +(l>>3), colblock (l&7)^(l>>3)  (inverse swizzle).
//
//    Schedule invariants (per-wave load issue order, steady state, tile kt):
//      P4 of kt-1: (kt+1).H1-3 (6 loads) -> vmcnt(6)
//      P1 of kt  : (kt+1).H4   (2 loads)
//      P4 of kt  : (kt+2).H1-3 (6 loads) -> vmcnt(6) drains all of tile kt+1
__global__ __launch_bounds__(512, 2) void main_gemm(
    const unsigned short* __restrict__ xb, const unsigned short* __restrict__ wb,
    const unsigned short* __restrict__ taug, const unsigned short* __restrict__ baug,
    const float* __restrict__ bias, float* __restrict__ out) {
  __shared__ __align__(1024) unsigned short lds[65536];  // 128 KiB

  const int tid = threadIdx.x;
  const int wave = tid >> 6;
  const int lane = tid & 63;
  const int wm = wave >> 2;          // 0..1 -> rows wm*128..+128
  const int wn = wave & 3;           // 0..3 -> cols wn*64..+64
  const int fr = lane & 15;
  const int fq = (lane >> 4) << 3;   // 0,8,16,24 (ushort col offset)

  // XCD-aware bijective swizzle: nwg = 1024 = 8 * 128
  const int orig = blockIdx.x;
  const int swb = (orig & 7) * 128 + (orig >> 3);
  const int tile_m = swb >> 4;       // 0..63
  const int tile_n = swb & 15;       // 0..15
  const int m0 = tile_m * 256;
  const int n0 = tile_n * 256;
  const int batch = tile_m >> 3;     // 2048 rows per batch, 8 tiles per batch

  // --- staging source: lane l of a 1024B chunk (8 rows x 128B) writes LDS
  //     ushorts [l*8, l*8+8) linearly; logical source is row +(l>>3),
  //     colblock (l&7)^(l>>3) (the swizzle is its own inverse). ---
  const int laneoff = (lane >> 3) * DK + (((lane & 7) ^ (lane >> 3)) << 3);
  const unsigned short* aSrc = xb + (size_t)(m0 + 16 * wave) * DK + laneoff;
  const unsigned short* bSrc = wb + (size_t)(n0 + 16 * wave) * DK + laneoff;

// stage half h (128 rows) of A or B for K-tile kt into dbuf d (2 async16)
#define STG_A(d, h, kt) do {                                                        \
    async16(aSrc + (size_t)(h) * (128 * DK) + ((size_t)(kt) << 6),                  \
            &lds[(d) * 32768 + (h) * 8192 + wave * 1024]);                          \
    async16(aSrc + (size_t)(h) * (128 * DK) + 8 * DK + ((size_t)(kt) << 6),         \
            &lds[(d) * 32768 + (h) * 8192 + wave * 1024 + 512]);                    \
  } while (0)
#define STG_B(d, h, kt) do {                                                        \
    async16(bSrc + (size_t)(h) * (128 * DK) + ((size_t)(kt) << 6),                  \
            &lds[(d) * 32768 + 16384 + (h) * 8192 + wave * 1024]);                  \
    async16(bSrc + (size_t)(h) * (128 * DK) + 8 * DK + ((size_t)(kt) << 6),         \
            &lds[(d) * 32768 + 16384 + (h) * 8192 + wave * 1024 + 512]);            \
  } while (0)

  // --- fragment read bases: physical col = (ks*32 + fq) ^ ((fr&7)<<3).
  //     ks flips bit 5 of the swizzled col -> keep two bases per operand. ---
  const int colb0 = fq ^ ((fr & 7) << 3);
  const int colb1 = colb0 ^ 32;
  const int aRd0 = wm * 8192 + fr * 64 + colb0;
  const int aRd1 = wm * 8192 + fr * 64 + colb1;
  const int bRd0 = 16384 + wn * 4096 + fr * 64 + colb0;
  const int bRd1 = 16384 + wn * 4096 + fr * 64 + colb1;

#define RD_A(d, t, ks)                                                              \
  (*(const bf16x8*)&lds[(d) * 32768 + ((ks) ? aRd1 : aRd0) + (t) * 1024])
#define RD_B(d, u, ks)                                                              \
  (*(const bf16x8*)&lds[(d) * 32768 + ((ks) ? bRd1 : bRd0) + (u) * 1024])

  floatx4 acc[8][4];
#pragma unroll
  for (int t = 0; t < 8; ++t)
#pragma unroll
    for (int u = 0; u < 4; ++u) acc[t][u] = (floatx4){0.f, 0.f, 0.f, 0.f};

  bf16x8 a[4][2];    // A frags of current rowhalf (t x ks)
  bf16x8 b0[2][2];   // B frags cols 0-31 of wave (u x ks)
  bf16x8 b1[2][2];   // B frags cols 32-63 of wave

  // --- prologue: tile0 H1-4, tile1 H1-3; drain tile0 (6 left in flight) ---
  STG_A(0, 0, 0); STG_A(0, 1, 0); STG_B(0, 0, 0); STG_B(0, 1, 0);
  STG_A(1, 0, 1); STG_A(1, 1, 1); STG_B(1, 0, 1);
  asm volatile("s_waitcnt vmcnt(6)" ::: "memory");
  __builtin_amdgcn_s_barrier();

#define TILE(d, kt) do {                                                            \
    /* ---- P1: quadrant (rh0, ch0); stage H4 of tile kt+1 ---- */                  \
    _Pragma("unroll")                                                               \
    for (int t = 0; t < 4; ++t) { a[t][0] = RD_A(d, t, 0); a[t][1] = RD_A(d, t, 1); } \
    _Pragma("unroll")                                                               \
    for (int u = 0; u < 2; ++u) { b0[u][0] = RD_B(d, u, 0); b0[u][1] = RD_B(d, u, 1); } \
    if ((kt) + 1 < 64) STG_B(1 - (d), 1, (kt) + 1);                                 \
    __builtin_amdgcn_s_barrier();                                                   \
    asm volatile("s_waitcnt lgkmcnt(0)" ::: "memory");                              \
    __builtin_amdgcn_s_setprio(1);                                                  \
    _Pragma("unroll")                                                               \
    for (int t = 0; t < 4; ++t)                                                     \
      _Pragma("unroll")                                                             \
      for (int u = 0; u < 2; ++u) {                                                 \
        acc[t][u] = __builtin_amdgcn_mfma_f32_16x16x32_bf16(a[t][0], b0[u][0], acc[t][u], 0, 0, 0); \
        acc[t][u] = __builtin_amdgcn_mfma_f32_16x16x32_bf16(a[t][1], b0[u][1], acc[t][u], 0, 0, 0); \
      }                                                                             \
    __builtin_amdgcn_s_setprio(0);                                                  \
    __builtin_amdgcn_s_barrier();                                                   \
    /* ---- P2: quadrant (rh0, ch1) ---- */                                         \
    _Pragma("unroll")                                                               \
    for (int u = 0; u < 2; ++u) { b1[u][0] = RD_B(d, u + 2, 0); b1[u][1] = RD_B(d, u + 2, 1); } \
    __builtin_amdgcn_s_barrier();                                                   \
    asm volatile("s_waitcnt lgkmcnt(0)" ::: "memory");                              \
    __builtin_amdgcn_s_setprio(1);                                                  \
    _Pragma("unroll")                                                               \
    for (int t = 0; t < 4; ++t)                                                     \
      _Pragma("unroll")                                                             \
      for (int u = 0; u < 2; ++u) {                                                 \
        acc[t][u + 2] = __builtin_amdgcn_mfma_f32_16x16x32_bf16(a[t][0], b1[u][0], acc[t][u + 2], 0, 0, 0); \
        acc[t][u + 2] = __builtin_amdgcn_mfma_f32_16x16x32_bf16(a[t][1], b1[u][1], acc[t][u + 2], 0, 0, 0); \
      }                                                                             \
    __builtin_amdgcn_s_setprio(0);                                                  \
    __builtin_amdgcn_s_barrier();                                                   \
    /* ---- P3: quadrant (rh1, ch0) ---- */                                         \
    _Pragma("unroll")                                                               \
    for (int t = 0; t < 4; ++t) { a[t][0] = RD_A(d, t + 4, 0); a[t][1] = RD_A(d, t + 4, 1); } \
    __builtin_amdgcn_s_barrier();                                                   \
    asm volatile("s_waitcnt lgkmcnt(0)" ::: "memory");                              \
    __builtin_amdgcn_s_setprio(1);                                                  \
    _Pragma("unroll")                                                               \
    for (int t = 0; t < 4; ++t)                                                     \
      _Pragma("unroll")                                                             \
      for (int u = 0; u < 2; ++u) {                                                 \
        acc[t + 4][u] = __builtin_amdgcn_mfma_f32_16x16x32_bf16(a[t][0], b0[u][0], acc[t + 4][u], 0, 0, 0); \
        acc[t + 4][u] = __builtin_amdgcn_mfma_f32_16x16x32_bf16(a[t][1], b0[u][1], acc[t + 4][u], 0, 0, 0); \
      }                                                                             \
    __builtin_amdgcn_s_setprio(0);                                                  \
    __builtin_amdgcn_s_barrier();                                                   \
    /* ---- P4: stage H1-3 of tile kt+2 (buf reads ended at P3);             */     \
    /*      counted vmcnt(6) covers everything tile kt+1 needs; reg-only MFMA */    \
    if ((kt) + 2 < 64) {                                                            \
      STG_A(d, 0, (kt) + 2); STG_A(d, 1, (kt) + 2); STG_B(d, 0, (kt) + 2);          \
      asm volatile("s_waitcnt vmcnt(6)" ::: "memory");                              \
    } else {                                                                        \
      asm volatile("s_waitcnt vmcnt(0)" ::: "memory");                              \
    }                                                                               \
    __builtin_amdgcn_s_barrier();                                                   \
    __builtin_amdgcn_s_setprio(1);                                                  \
    _Pragma("unroll")                                                               \
    for (int t = 0; t < 4; ++t)                                                     \
      _Pragma("unroll")                                                             \
      for (int u = 0; u < 2; ++u) {                                                 \
        acc[t + 4][u + 2] = __builtin_amdgcn_mfma_f32_16x16x32_bf16(a[t][0], b1[u][0], acc[t + 4][u + 2], 0, 0, 0); \
        acc[t + 4][u + 2] = __builtin_amdgcn_mfma_f32_16x16x32_bf16(a[t][1], b1[u][1], acc[t + 4][u + 2], 0, 0, 0); \
      }                                                                             \
    __builtin_amdgcn_s_setprio(0);                                                  \
    __builtin_amdgcn_s_barrier();                                                   \
  } while (0)

  for (int it = 0; it < 32; ++it) {
    const int kt0 = it * 2;
    TILE(0, kt0);
    TILE(1, kt0 + 1);
  }

  // --- adapter step: one K=32 MFMA round from taug/baug (cols 16-31 zero) ---
  {
    const unsigned short* tA = taug + (size_t)(m0 + wm * 128 + fr) * 32 + fq;
    const unsigned short* tB = baug + ((size_t)batch * DN + n0 + wn * 64 + fr) * 32 + fq;
    bf16x8 av[8], bv[4];
#pragma unroll
    for (int t = 0; t < 8; ++t) av[t] = *(const bf16x8*)(tA + (size_t)t * 512);
#pragma unroll
    for (int u = 0; u < 4; ++u) bv[u] = *(const bf16x8*)(tB + (size_t)u * 512);
#pragma unroll
    for (int t = 0; t < 8; ++t)
#pragma unroll
      for (int u = 0; u < 4; ++u)
        acc[t][u] = __builtin_amdgcn_mfma_f32_16x16x32_bf16(av[t], bv[u], acc[t][u], 0, 0, 0);
  }

  // --- epilogue: C/D layout col=lane&15, row=(lane>>4)*4+j; add bias ---
  const int rowq = (lane >> 4) * 4;
#pragma unroll
  for (int u = 0; u < 4; ++u) {
    const int col = n0 + wn * 64 + u * 16 + fr;
    const float bvv = bias[col];
#pragma unroll
    for (int t = 0; t < 8; ++t) {
      float* po = out + (size_t)(m0 + wm * 128 + t * 16 + rowq) * DN + col;
#pragma unroll
      for (int j = 0; j < 4; ++j) po[(size_t)j * DN] = acc[t][u][j] + bvv;
    }
  }
#undef TILE
#undef RD_A
#undef RD_B
#undef STG_A
#undef STG_B
}

// ---------------------------------------------------------------------------
extern "C" void kernel_launch(void* const* d_in, const int* in_sizes, int n_in,
                              void* d_out, int out_size, void* d_ws, size_t ws_size,
                              hipStream_t stream) {
  (void)in_sizes; (void)n_in; (void)out_size; (void)ws_size;
  const float* x             = (const float*)d_in[0];
  const float* weight        = (const float*)d_in[1];
  const float* bias          = (const float*)d_in[2];
  const float* module_logits = (const float*)d_in[3];
  const float* lora_a        = (const float*)d_in[4];
  const float* lora_b        = (const float*)d_in[5];
  const void*  task_ids      = d_in[6];
  float* out = (float*)d_out;

  // workspace layout (all 16B-aligned); total ~165 MB
  char* ws = (char*)d_ws;
  unsigned short* xb   = (unsigned short*)(ws);                  // 16384*4096*2 = 134217728
  unsigned short* wb   = (unsigned short*)(ws + 134217728);      // 4096*4096*2  = 33554432
  unsigned short* taug = (unsigned short*)(ws + 167772160);      // 16384*32*2   = 1048576
  unsigned short* baug = (unsigned short*)(ws + 168820736);      // 8*4096*32*2  = 2097152
  unsigned short* abft = (unsigned short*)(ws + 170917888);      // 8*16*4096*2  = 1048576
  float*          tf32 = (float*)(ws + 171966464);               // 16384*16*4   = 1048576
  float*          mw   = (float*)(ws + 173015040);               // 256

  hipLaunchKernelGGL(prep_mw_kernel, dim3(1), dim3(64), 0, stream,
                     module_logits, task_ids, mw);
  hipLaunchKernelGGL(prep_a_kernel, dim3(16, 8), dim3(256), 0, stream,
                     lora_a, mw, abft);
  hipLaunchKernelGGL(prep_b_kernel, dim3(16, 8), dim3(256), 0, stream,
                     lora_b, mw, baug);
  hipLaunchKernelGGL(conv_f32_to_bf16, dim3(2048), dim3(256), 0, stream,
                     weight, wb, (long long)(4096LL * 4096 / 4));
  hipLaunchKernelGGL(conv_f32_to_bf16, dim3(8192), dim3(256), 0, stream,
                     x, xb, (long long)(16384LL * 4096 / 4));
  hipMemsetAsync(tf32, 0, (size_t)M_TOT * RANK * sizeof(float), stream);
  hipLaunchKernelGGL(t_gemm_kernel, dim3(256, 4), dim3(256), 0, stream,
                     xb, abft, tf32);
  hipLaunchKernelGGL(t_final_kernel, dim3(1024), dim3(256), 0, stream,
                     tf32, taug);
  hipLaunchKernelGGL(main_gemm, dim3(1024), dim3(512), 0, stream,
                     xb, wb, taug, baug, bias, out);
}

// Round 3
// 962.895 us; speedup vs baseline: 1.2409x; 1.0399x over previous
//
#include <hip/hip_runtime.h>
#include <hip/hip_bf16.h>
#include <cstdint>
#include <cstddef>

typedef __attribute__((ext_vector_type(4))) float floatx4;
typedef __attribute__((ext_vector_type(8))) __bf16 bf16x8;

#define BS 8
#define SEQ 2048
#define M_TOT 16384
#define DK 4096
#define DN 4096
#define NSK 8
#define RANK 16

__device__ __forceinline__ unsigned short f2bf(float f) {
  union { __hip_bfloat16 h; unsigned short u; } v;
  v.h = __float2bfloat16(f);
  return v.u;
}

// async 16B global->LDS (wave-uniform LDS base + lane*16)
__device__ __forceinline__ void async16(const void* g, void* l) {
  __builtin_amdgcn_global_load_lds(
      (const __attribute__((address_space(1))) unsigned int*)g,
      (__attribute__((address_space(3))) unsigned int*)l, 16, 0, 0);
}

// Mixing weights for batch b: sigmoid(logits[task[b]][s]) sum-normalized.
__device__ __forceinline__ void compute_mw(const float* __restrict__ logits,
                                           const void* __restrict__ task_raw,
                                           int b, float* w) {
  const int* t32 = (const int*)task_raw;
  bool is64 = true;
#pragma unroll
  for (int bb = 0; bb < BS; ++bb)
    if (t32[2 * bb + 1] != 0) is64 = false;  // high words nonzero => int32 data
  int task = is64 ? t32[2 * b] : t32[b];
  float sum = 0.f;
#pragma unroll
  for (int s = 0; s < NSK; ++s) {
    w[s] = 1.0f / (1.0f + expf(-logits[task * NSK + s]));
    sum += w[s];
  }
  float inv = 1.0f / (sum + 1e-12f);
#pragma unroll
  for (int s = 0; s < NSK; ++s) w[s] *= inv;
}

// ---------------------------------------------------------------------------
// 1. Merged prep: z=0 -> abft (A_bfT[b][r][d]), z=1 -> baug (B rows, /rank,
//    zero-padded to 32). mw recomputed per block (8 expf/thread, trivial).
__global__ __launch_bounds__(256) void prep_ab_kernel(
    const float* __restrict__ lora_a, const float* __restrict__ lora_b,
    const float* __restrict__ logits, const void* __restrict__ task_raw,
    unsigned short* __restrict__ abft, unsigned short* __restrict__ baug) {
  int b = blockIdx.y;
  float w[NSK];
  compute_mw(logits, task_raw, b, w);
  if (blockIdx.z == 0) {
    int d = blockIdx.x * 256 + threadIdx.x;
    float acc[RANK];
#pragma unroll
    for (int r = 0; r < RANK; ++r) acc[r] = 0.f;
    for (int s = 0; s < NSK; ++s) {
      const float4* p = (const float4*)&lora_a[((size_t)s * DK + d) * RANK];
#pragma unroll
      for (int q = 0; q < 4; ++q) {
        float4 v = p[q];
        acc[q * 4 + 0] += w[s] * v.x;
        acc[q * 4 + 1] += w[s] * v.y;
        acc[q * 4 + 2] += w[s] * v.z;
        acc[q * 4 + 3] += w[s] * v.w;
      }
    }
#pragma unroll
    for (int r = 0; r < RANK; ++r)
      abft[((size_t)b * RANK + r) * DK + d] = f2bf(acc[r]);
  } else {
    int n = blockIdx.x * 256 + threadIdx.x;
    unsigned short ov[32];
#pragma unroll
    for (int r = 0; r < RANK; ++r) {
      float acc = 0.f;
#pragma unroll
      for (int s = 0; s < NSK; ++s)
        acc += w[s] * lora_b[((size_t)s * RANK + r) * DN + n];
      ov[r] = f2bf(acc * 0.0625f);  // fold the /rank here
    }
#pragma unroll
    for (int r = RANK; r < 32; ++r) ov[r] = 0;
    uint4* dst = (uint4*)&baug[((size_t)b * DN + n) * 32];
    const uint4* sv = (const uint4*)ov;
    dst[0] = sv[0]; dst[1] = sv[1]; dst[2] = sv[2]; dst[3] = sv[3];
  }
}

// ---------------------------------------------------------------------------
// 2. Merged fp32->bf16 conversion: weight (4M float4) then x (16.7M float4).
__global__ __launch_bounds__(256) void conv_all(
    const float* __restrict__ wsrc, const float* __restrict__ xsrc,
    unsigned short* __restrict__ wb, unsigned short* __restrict__ xb) {
  const long long n4w = 4194304LL;          // 4096*4096/4
  const long long n4t = 20971520LL;         // + 16384*4096/4
  long long stride = (long long)gridDim.x * 256;
  for (long long i = (long long)blockIdx.x * 256 + threadIdx.x; i < n4t;
       i += stride) {
    const float4* s; ushort4* d; long long j;
    if (i < n4w) { s = (const float4*)wsrc; d = (ushort4*)wb; j = i; }
    else         { s = (const float4*)xsrc; d = (ushort4*)xb; j = i - n4w; }
    float4 v = s[j];
    ushort4 o;
    o.x = f2bf(v.x); o.y = f2bf(v.y); o.z = f2bf(v.z); o.w = f2bf(v.w);
    d[j] = o;
  }
}

// ---------------------------------------------------------------------------
// 3. t = xb @ A_bfT^T, one 16-row mtile per block; 4 waves each take a
//    K=1024 chunk (32 MFMA, 64 b128 loads), LDS tree-reduce, write taug
//    bf16 directly (cols 16-31 zeroed). No atomics / memset / final pass.
__global__ __launch_bounds__(256) void t_gemm_kernel(
    const unsigned short* __restrict__ xb, const unsigned short* __restrict__ abft,
    unsigned short* __restrict__ taug) {
  __shared__ float red[4][256];
  const int wave = threadIdx.x >> 6;
  const int lane = threadIdx.x & 63;
  const int row0 = blockIdx.x * 16;
  const int b = row0 >> 11;                 // /2048
  const int fr = lane & 15;
  const int fq = (lane >> 4) * 8;
  const unsigned short* pa = xb + (size_t)(row0 + fr) * DK + wave * 1024 + fq;
  const unsigned short* pb = abft + ((size_t)b * RANK + fr) * DK + wave * 1024 + fq;
  floatx4 acc = {0.f, 0.f, 0.f, 0.f};
  for (int k = 0; k < 1024; k += 32) {
    bf16x8 av = *(const bf16x8*)(pa + k);
    bf16x8 bv = *(const bf16x8*)(pb + k);
    acc = __builtin_amdgcn_mfma_f32_16x16x32_bf16(av, bv, acc, 0, 0, 0);
  }
  const int rowq = (lane >> 4) * 4;
#pragma unroll
  for (int j = 0; j < 4; ++j) red[wave][(rowq + j) * 16 + fr] = acc[j];
  __syncthreads();
  int i = threadIdx.x;  // 0..255 -> (row i>>4, col i&15)
  float v = red[0][i] + red[1][i] + red[2][i] + red[3][i];
  int r = i >> 4, c = i & 15;
  taug[(size_t)(row0 + r) * 32 + c] = f2bf(v);
  taug[(size_t)(row0 + r) * 32 + 16 + c] = 0;
}

// ---------------------------------------------------------------------------
// 4. Main GEMM — 256x256 tile, BK=64, 8 waves (2Mx4N, 128x64 per wave),
//    8-phase schedule (T3) + counted vmcnt(6) (T4) + T2 st_16x32 swizzle
//    (col ^= (row&7)<<3) + setprio (T5) + bijective XCD swizzle (T1).
//    Round-3 changes: staging spread 2 gloads/phase (64-row quarters, one
//    async16/wave), each quarter staged only after its last reader phase;
//    P4 reordered {stage, MFMA, vmcnt, barrier} (7 barriers/K-tile).
//
//    Quarter read/stage windows (buf d = tile kt):
//      A q0 (rows 0-63,  wm0) & q2 (128-191, wm1): read P1 -> stage kt+2 @ P2
//      A q1 (64-127) & q3 (192-255):               read P3 -> stage kt+2 @ P4
//      B q0-q3: each wn-wave reads its 64-row span at P1+P2 -> B q0,q1(kt+2)
//               @ P3; B q2,q3(kt+1) @ P1 of kt (into buf 1-d, idle this tile)
//    Issue order entering P4 of kt (14 outstanding): [kt+1: Aq0,Aq2 | Bq0,Bq1
//    | Aq1,Aq3 | Bq2,Bq3][kt+2: Aq0,Aq2 | Bq0,Bq1 | Aq1,Aq3] -> vmcnt(6)
//    retires exactly tile kt+1's 8 loads.
__global__ __launch_bounds__(512, 2) void main_gemm(
    const unsigned short* __restrict__ xb, const unsigned short* __restrict__ wb,
    const unsigned short* __restrict__ taug, const unsigned short* __restrict__ baug,
    const float* __restrict__ bias, float* __restrict__ out) {
  __shared__ __align__(1024) unsigned short lds[65536];  // 128 KiB

  const int tid = threadIdx.x;
  const int wave = tid >> 6;
  const int lane = tid & 63;
  const int wm = wave >> 2;          // 0..1 -> rows wm*128..+128
  const int wn = wave & 3;           // 0..3 -> cols wn*64..+64
  const int fr = lane & 15;
  const int fq = (lane >> 4) << 3;   // 0,8,16,24 (ushort col offset)

  // XCD-aware bijective swizzle: nwg = 1024 = 8 * 128
  const int orig = blockIdx.x;
  const int swb = (orig & 7) * 128 + (orig >> 3);
  const int tile_m = swb >> 4;       // 0..63
  const int tile_n = swb & 15;       // 0..15
  const int m0 = tile_m * 256;
  const int n0 = tile_n * 256;
  const int batch = tile_m >> 3;     // 2048 rows per batch, 8 tiles per batch

  // --- staging: quarter = 64 rows x 64 cols = 8 KB = 8 waves x 1 async16.
  //     Wave w covers rows [q*64 + w*8, +8); lane l: row +(l>>3), colblock
  //     (l&7)^(l>>3) (inverse of the read swizzle; linear LDS dest). ---
  const int lrow = lane >> 3;
  const int lcol = (((lane & 7) ^ lrow) << 3);
  const unsigned short* aQ = xb + (size_t)(m0 + wave * 8 + lrow) * DK + lcol;
  const unsigned short* bQ = wb + (size_t)(n0 + wave * 8 + lrow) * DK + lcol;

#define STG_AQ(d, q, kt)                                                            \
  async16(aQ + (size_t)(q) * (64 * DK) + ((size_t)(kt) << 6),                       \
          &lds[(d) * 32768 + (q) * 4096 + wave * 512])
#define STG_BQ(d, q, kt)                                                            \
  async16(bQ + (size_t)(q) * (64 * DK) + ((size_t)(kt) << 6),                       \
          &lds[(d) * 32768 + 16384 + (q) * 4096 + wave * 512])

  // --- fragment read bases: physical col = (ks*32 + fq) ^ ((fr&7)<<3). ---
  const int colb0 = fq ^ ((fr & 7) << 3);
  const int colb1 = colb0 ^ 32;
  const int aRd0 = wm * 8192 + fr * 64 + colb0;
  const int aRd1 = wm * 8192 + fr * 64 + colb1;
  const int bRd0 = 16384 + wn * 4096 + fr * 64 + colb0;
  const int bRd1 = 16384 + wn * 4096 + fr * 64 + colb1;

#define RD_A(d, t, ks)                                                              \
  (*(const bf16x8*)&lds[(d) * 32768 + ((ks) ? aRd1 : aRd0) + (t) * 1024])
#define RD_B(d, u, ks)                                                              \
  (*(const bf16x8*)&lds[(d) * 32768 + ((ks) ? bRd1 : bRd0) + (u) * 1024])

  floatx4 acc[8][4];
#pragma unroll
  for (int t = 0; t < 8; ++t)
#pragma unroll
    for (int u = 0; u < 4; ++u) acc[t][u] = (floatx4){0.f, 0.f, 0.f, 0.f};

  bf16x8 a[4][2];    // A frags of current rowhalf (t x ks)
  bf16x8 b0[2][2];   // B frags cols 0-31 of wave (u x ks)
  bf16x8 b1[2][2];   // B frags cols 32-63 of wave

  // --- prologue: tile0 all 8 quarters, tile1 first 6; drain tile0 ---
  STG_AQ(0, 0, 0); STG_AQ(0, 2, 0); STG_BQ(0, 0, 0); STG_BQ(0, 1, 0);
  STG_AQ(0, 1, 0); STG_AQ(0, 3, 0); STG_BQ(0, 2, 0); STG_BQ(0, 3, 0);
  STG_AQ(1, 0, 1); STG_AQ(1, 2, 1); STG_BQ(1, 0, 1); STG_BQ(1, 1, 1);
  STG_AQ(1, 1, 1); STG_AQ(1, 3, 1);
  asm volatile("s_waitcnt vmcnt(6)" ::: "memory");
  __builtin_amdgcn_s_barrier();

#define TILE(d, kt) do {                                                            \
    /* ---- P1: stage kt+1 B q2,q3; read (rh0,ch0); MFMA quadrant 1 ---- */         \
    if ((kt) + 1 < 64) { STG_BQ(1 - (d), 2, (kt) + 1); STG_BQ(1 - (d), 3, (kt) + 1); } \
    _Pragma("unroll")                                                               \
    for (int t = 0; t < 4; ++t) { a[t][0] = RD_A(d, t, 0); a[t][1] = RD_A(d, t, 1); } \
    _Pragma("unroll")                                                               \
    for (int u = 0; u < 2; ++u) { b0[u][0] = RD_B(d, u, 0); b0[u][1] = RD_B(d, u, 1); } \
    asm volatile("s_waitcnt lgkmcnt(8)" ::: "memory");                              \
    __builtin_amdgcn_s_barrier();                                                   \
    asm volatile("s_waitcnt lgkmcnt(0)" ::: "memory");                              \
    __builtin_amdgcn_s_setprio(1);                                                  \
    _Pragma("unroll")                                                               \
    for (int t = 0; t < 4; ++t)                                                     \
      _Pragma("unroll")                                                             \
      for (int u = 0; u < 2; ++u) {                                                 \
        acc[t][u] = __builtin_amdgcn_mfma_f32_16x16x32_bf16(a[t][0], b0[u][0], acc[t][u], 0, 0, 0); \
        acc[t][u] = __builtin_amdgcn_mfma_f32_16x16x32_bf16(a[t][1], b0[u][1], acc[t][u], 0, 0, 0); \
      }                                                                             \
    __builtin_amdgcn_s_setprio(0);                                                  \
    __builtin_amdgcn_s_barrier();                                                   \
    /* ---- P2: stage kt+2 A q0,q2 (read-done at P1); read ch1; MFMA q2 ---- */     \
    if ((kt) + 2 < 64) { STG_AQ(d, 0, (kt) + 2); STG_AQ(d, 2, (kt) + 2); }          \
    _Pragma("unroll")                                                               \
    for (int u = 0; u < 2; ++u) { b1[u][0] = RD_B(d, u + 2, 0); b1[u][1] = RD_B(d, u + 2, 1); } \
    __builtin_amdgcn_s_barrier();                                                   \
    asm volatile("s_waitcnt lgkmcnt(0)" ::: "memory");                              \
    __builtin_amdgcn_s_setprio(1);                                                  \
    _Pragma("unroll")                                                               \
    for (int t = 0; t < 4; ++t)                                                     \
      _Pragma("unroll")                                                             \
      for (int u = 0; u < 2; ++u) {                                                 \
        acc[t][u + 2] = __builtin_amdgcn_mfma_f32_16x16x32_bf16(a[t][0], b1[u][0], acc[t][u + 2], 0, 0, 0); \
        acc[t][u + 2] = __builtin_amdgcn_mfma_f32_16x16x32_bf16(a[t][1], b1[u][1], acc[t][u + 2], 0, 0, 0); \
      }                                                                             \
    __builtin_amdgcn_s_setprio(0);                                                  \
    __builtin_amdgcn_s_barrier();                                                   \
    /* ---- P3: stage kt+2 B q0,q1 (B read-done at P2); read rh1; MFMA q3 ---- */   \
    if ((kt) + 2 < 64) { STG_BQ(d, 0, (kt) + 2); STG_BQ(d, 1, (kt) + 2); }          \
    _Pragma("unroll")                                                               \
    for (int t = 0; t < 4; ++t) { a[t][0] = RD_A(d, t + 4, 0); a[t][1] = RD_A(d, t + 4, 1); } \
    __builtin_amdgcn_s_barrier();                                                   \
    asm volatile("s_waitcnt lgkmcnt(0)" ::: "memory");                              \
    __builtin_amdgcn_s_setprio(1);                                                  \
    _Pragma("unroll")                                                               \
    for (int t = 0; t < 4; ++t)                                                     \
      _Pragma("unroll")                                                             \
      for (int u = 0; u < 2; ++u) {                                                 \
        acc[t + 4][u] = __builtin_amdgcn_mfma_f32_16x16x32_bf16(a[t][0], b0[u][0], acc[t + 4][u], 0, 0, 0); \
        acc[t + 4][u] = __builtin_amdgcn_mfma_f32_16x16x32_bf16(a[t][1], b0[u][1], acc[t + 4][u], 0, 0, 0); \
      }                                                                             \
    __builtin_amdgcn_s_setprio(0);                                                  \
    __builtin_amdgcn_s_barrier();                                                   \
    /* ---- P4: stage kt+2 A q1,q3 (read-done at P3); reg-only MFMA q4;      */     \
    /*      vmcnt AFTER the MFMAs (hidden), single trailing barrier ---- */         \
    if ((kt) + 2 < 64) { STG_AQ(d, 1, (kt) + 2); STG_AQ(d, 3, (kt) + 2); }          \
    __builtin_amdgcn_s_setprio(1);                                                  \
    _Pragma("unroll")                                                               \
    for (int t = 0; t < 4; ++t)                                                     \
      _Pragma("unroll")                                                             \
      for (int u = 0; u < 2; ++u) {                                                 \
        acc[t + 4][u + 2] = __builtin_amdgcn_mfma_f32_16x16x32_bf16(a[t][0], b1[u][0], acc[t + 4][u + 2], 0, 0, 0); \
        acc[t + 4][u + 2] = __builtin_amdgcn_mfma_f32_16x16x32_bf16(a[t][1], b1[u][1], acc[t + 4][u + 2], 0, 0, 0); \
      }                                                                             \
    __builtin_amdgcn_s_setprio(0);                                                  \
    if ((kt) + 2 < 64) { asm volatile("s_waitcnt vmcnt(6)" ::: "memory"); }         \
    else               { asm volatile("s_waitcnt vmcnt(0)" ::: "memory"); }         \
    __builtin_amdgcn_s_barrier();                                                   \
  } while (0)

  for (int it = 0; it < 32; ++it) {
    const int kt0 = it * 2;
    TILE(0, kt0);
    TILE(1, kt0 + 1);
  }

  // --- adapter step: one K=32 MFMA round from taug/baug (cols 16-31 zero) ---
  {
    const unsigned short* tA = taug + (size_t)(m0 + wm * 128 + fr) * 32 + fq;
    const unsigned short* tB = baug + ((size_t)batch * DN + n0 + wn * 64 + fr) * 32 + fq;
    bf16x8 av[8], bv[4];
#pragma unroll
    for (int t = 0; t < 8; ++t) av[t] = *(const bf16x8*)(tA + (size_t)t * 512);
#pragma unroll
    for (int u = 0; u < 4; ++u) bv[u] = *(const bf16x8*)(tB + (size_t)u * 512);
#pragma unroll
    for (int t = 0; t < 8; ++t)
#pragma unroll
      for (int u = 0; u < 4; ++u)
        acc[t][u] = __builtin_amdgcn_mfma_f32_16x16x32_bf16(av[t], bv[u], acc[t][u], 0, 0, 0);
  }

  // --- epilogue: C/D layout col=lane&15, row=(lane>>4)*4+j; add bias ---
  const int rowq = (lane >> 4) * 4;
#pragma unroll
  for (int u = 0; u < 4; ++u) {
    const int col = n0 + wn * 64 + u * 16 + fr;
    const float bvv = bias[col];
#pragma unroll
    for (int t = 0; t < 8; ++t) {
      float* po = out + (size_t)(m0 + wm * 128 + t * 16 + rowq) * DN + col;
#pragma unroll
      for (int j = 0; j < 4; ++j) po[(size_t)j * DN] = acc[t][u][j] + bvv;
    }
  }
#undef TILE
#undef RD_A
#undef RD_B
#undef STG_AQ
#undef STG_BQ
}

// ---------------------------------------------------------------------------
extern "C" void kernel_launch(void* const* d_in, const int* in_sizes, int n_in,
                              void* d_out, int out_size, void* d_ws, size_t ws_size,
                              hipStream_t stream) {
  (void)in_sizes; (void)n_in; (void)out_size; (void)ws_size;
  const float* x             = (const float*)d_in[0];
  const float* weight        = (const float*)d_in[1];
  const float* bias          = (const float*)d_in[2];
  const float* module_logits = (const float*)d_in[3];
  const float* lora_a        = (const float*)d_in[4];
  const float* lora_b        = (const float*)d_in[5];
  const void*  task_ids      = d_in[6];
  float* out = (float*)d_out;

  // workspace layout (all 16B-aligned); total ~172 MB
  char* ws = (char*)d_ws;
  unsigned short* xb   = (unsigned short*)(ws);                  // 16384*4096*2 = 134217728
  unsigned short* wb   = (unsigned short*)(ws + 134217728);      // 4096*4096*2  = 33554432
  unsigned short* taug = (unsigned short*)(ws + 167772160);      // 16384*32*2   = 1048576
  unsigned short* baug = (unsigned short*)(ws + 168820736);      // 8*4096*32*2  = 2097152
  unsigned short* abft = (unsigned short*)(ws + 170917888);      // 8*16*4096*2  = 1048576

  hipLaunchKernelGGL(prep_ab_kernel, dim3(16, 8, 2), dim3(256), 0, stream,
                     lora_a, lora_b, module_logits, task_ids, abft, baug);
  hipLaunchKernelGGL(conv_all, dim3(4096), dim3(256), 0, stream,
                     weight, x, wb, xb);
  hipLaunchKernelGGL(t_gemm_kernel, dim3(1024), dim3(256), 0, stream,
                     xb, abft, taug);
  hipLaunchKernelGGL(main_gemm, dim3(1024), dim3(512), 0, stream,
                     xb, wb, taug, baug, bias, out);
}